// Round 4
// baseline (201.541 us; speedup 1.0000x reference)
//
#include <hip/hip_runtime.h>
#include <math.h>

typedef _Float16 half8v __attribute__((ext_vector_type(8)));
typedef _Float16 half4v __attribute__((ext_vector_type(4)));
typedef _Float16 half2v __attribute__((ext_vector_type(2)));
typedef float float4v __attribute__((ext_vector_type(4)));

// ---- problem constants ----
#define BB    4096
#define INV_ALPHA (1.0f/0.9f)

// ---- workspace float offsets ----
#define WS_CCW  0
#define WS_CCS  64
#define WS_LAM  128
#define WS_PM16 160     // 16 block-maxes of x2_step1 (written by k_pre)
#define WS_PM   256     // 256 block-maxes of xm
#define WS_XM   512
#define WS_X    (WS_XM + BB)
#define WS_X2   (WS_X + BB)
#define WS_H    16384   // halfs region starts at byte 65536
// half offsets within WS_H
#define H_NET   8192
#define H_W2    4096
#define H_W0    16384   // + net*2048 : [64 j][32 k] zero-padded
#define H_W3    20480   // + net*64

#if defined(__has_builtin)
#if __has_builtin(__builtin_amdgcn_rcpf)
#define FRCP(x) __builtin_amdgcn_rcpf(x)
#endif
#if __has_builtin(__builtin_amdgcn_exp2f)
#define FEXP2(x) __builtin_amdgcn_exp2f(x)
#endif
#if __has_builtin(__builtin_amdgcn_logf)
#define FLOG2(x) __builtin_amdgcn_logf(x)
#endif
#endif
#ifndef FRCP
#define FRCP(x) (1.0f / (x))
#endif
#ifndef FEXP2
#define FEXP2(x) exp2f(x)
#endif
#ifndef FLOG2
#define FLOG2(x) log2f(x)
#endif

// act: 64 rows x 64 halfs, 16B column-blocks XOR-swizzled by row
__device__ __forceinline__ int swz(int row, int cb) {
    return (row << 6) + (((cb ^ (row & 7)) & 7) << 3);
}

// relu + pack f32x4 -> f16x4
__device__ __forceinline__ half4v pk_relu4(float4v c) {
#if defined(__has_builtin) && __has_builtin(__builtin_amdgcn_cvt_pkrtz)
    half2v a = __builtin_bit_cast(half2v,
        __builtin_amdgcn_cvt_pkrtz(fmaxf(c[0], 0.0f), fmaxf(c[1], 0.0f)));
    half2v b = __builtin_bit_cast(half2v,
        __builtin_amdgcn_cvt_pkrtz(fmaxf(c[2], 0.0f), fmaxf(c[3], 0.0f)));
    half4v o; o[0] = a[0]; o[1] = a[1]; o[2] = b[0]; o[3] = b[1];
    return o;
#else
    half4v o;
    o[0] = (_Float16)fmaxf(c[0], 0.0f); o[1] = (_Float16)fmaxf(c[1], 0.0f);
    o[2] = (_Float16)fmaxf(c[2], 0.0f); o[3] = (_Float16)fmaxf(c[3], 0.0f);
    return o;
#endif
}

// integrand tail: ELU+1 -> 5 powers -> 1/(f+1) dot Wf -> relu
__device__ __forceinline__ float tail5(float y,
        float p0, float p1, float p2, float p3, float p4,
        float wf0, float wf1, float wf2, float wf3, float wf4) {
    if (y <= 0.0f) y = FEXP2(y * 1.44269504f) - 1.0f;   // elu
    float z = y + 1.0f;
    float lg = FLOG2(z);
    float g = wf0 * FRCP(FEXP2(p0 * lg) + 1.0f)
            + wf1 * FRCP(FEXP2(p1 * lg) + 1.0f)
            + wf2 * FRCP(FEXP2(p2 * lg) + 1.0f)
            + wf3 * FRCP(FEXP2(p3 * lg) + 1.0f)
            + wf4 * FRCP(FEXP2(p4 * lg) + 1.0f);
    return fmaxf(g, 0.0f);
}

// ---- fused setup: xm + maxes | weight repack | CC + lam | zero accumulators ----
__global__ void k_setup(const float* __restrict__ x_, const float* __restrict__ lw,
                        const float* __restrict__ sp,
                        const float* __restrict__ f1W0, const float* __restrict__ f1W1,
                        const float* __restrict__ f1W2, const float* __restrict__ f1W3,
                        const float* __restrict__ f2W0, const float* __restrict__ f2W1,
                        const float* __restrict__ f2W2, const float* __restrict__ f2W3,
                        float* __restrict__ ws, float* __restrict__ out) {
    _Float16* wh = (_Float16*)(ws + WS_H);
    const int blk = blockIdx.x, tid = threadIdx.x;
    if (blk < 256) {
        int wave = tid >> 6, lane = tid & 63;
        float vmax = -1e30f;
        for (int r = 0; r < 4; ++r) {
            int row = blk * 16 + wave * 4 + r;
            float v = 0.0f;
            for (int i = lane; i < 100; i += 64) v = fmaf(x_[row * 100 + i], lw[i], v);
            #pragma unroll
            for (int off = 32; off > 0; off >>= 1) v += __shfl_xor(v, off, 64);
            if (lane == 0) ws[WS_XM + row] = v;
            vmax = fmaxf(vmax, v);
        }
        __shared__ float sm[4];
        if (lane == 0) sm[wave] = vmax;
        __syncthreads();
        if (tid == 0)
            ws[WS_PM + blk] = fmaxf(fmaxf(sm[0], sm[1]), fmaxf(sm[2], sm[3]));
    } else if (blk < 272) {
        int t = (blk - 256) * 256 + tid;       // 0..4095
        wh[t]                = (_Float16)f1W1[t];
        wh[H_W2 + t]         = (_Float16)f1W2[t];
        wh[H_NET + t]        = (_Float16)f2W1[t];
        wh[H_NET + H_W2 + t] = (_Float16)f2W2[t];
        if (t < 2048) {
            int j = t >> 5, k = t & 31;
            wh[H_W0 + t]        = (k < 5) ? (_Float16)f1W0[j * 5 + k] : (_Float16)0.0f;
            wh[H_W0 + 2048 + t] = (k < 5) ? (_Float16)f2W0[j * 5 + k] : (_Float16)0.0f;
        }
        if (t < 64) {
            wh[H_W3 + t]      = (_Float16)f1W3[t];
            wh[H_W3 + 64 + t] = (_Float16)f2W3[t];
        }
    } else if (blk == 272) {
        if (tid == 64) ws[WS_LAM] = 1.0f / (1.0f + expf(-sp[0]));
        if (tid <= 50) {
            int s = tid;
            ws[WS_CCS + s] = cospif((float)s / 50.0f);
            float acc = 0.0f;
            for (int a = 0; a <= 50; ++a) {
                float w;
                if (a == 0) w = 1.0f;
                else if ((a & 1) == 0) w = 2.0f / (1.0f - (float)(a * a));
                else continue;
                float l;
                if (s == 0) l = 0.5f;
                else {
                    int m = (a * s) % 100;
                    l = cospif((float)m / 50.0f);
                    if (s == 50) l *= 0.5f;
                }
                acc += l * 0.04f * w;
            }
            ws[WS_CCW + s] = acc;
        }
    } else {
        // zero accumulation targets: out[0..BB) and out[2BB..3BB)
        int t = (blk - 273) * 256 + tid;       // 0..8191
        out[t < BB ? t : BB + t] = 0.0f;
    }
}

// between steps: x/x2 for step1, 16 partial maxes of x2, re-zero accumulators
__global__ void k_pre(float* __restrict__ ws, float* __restrict__ out) {
    int b = blockIdx.x * 256 + threadIdx.x;
    float lam = ws[WS_LAM];
    float m = ws[WS_XM + b];
    float xv  = (1.0f - lam) * m + lam * out[b];
    float x2v = (1.0f - lam) * m + lam * out[2 * BB + b];
    ws[WS_X + b] = xv;
    ws[WS_X2 + b] = x2v;
    out[b] = 0.0f;
    out[2 * BB + b] = 0.0f;
    __shared__ float red[256];
    red[threadIdx.x] = x2v;
    __syncthreads();
    #pragma unroll
    for (int off = 128; off > 0; off >>= 1) {
        if (threadIdx.x < off)
            red[threadIdx.x] = fmaxf(red[threadIdx.x], red[threadIdx.x + off]);
        __syncthreads();
    }
    if (threadIdx.x == 0) ws[WS_PM16 + blockIdx.x] = red[0];
}

// s-major, DOUBLE-s passes, spill-free variant:
//  - L1/L2 consume the two s-halves j-SEQUENTIALLY (Bf[2][4] live, not
//    Bf[2][2][4]) -> peak register pressure ~-32 VGPRs vs round-3.
//  - B-operand template: h is s-invariant, pre-packed to halfs once
//    (tpl[4]); per (j,n) only element 0 (x) is patched. Kills ~80 VALU
//    cvts per pass and frees the f32 h registers.
//  - biases in LDS (not registers).
// Group g (0..127) owns items [(g&63)*64, +64) for net (g>=64 ? f2 : f1);
// wave w (0..15) takes s-pairs (w, w+16) then (w+32, w+48); slots s>50 are
// dead (ccw=0); the w==15 f1 dead slot in mode 1 computes out_first.
__global__ __launch_bounds__(64, 2) void k_int(
    int mode, float* __restrict__ ws, const float* __restrict__ h_,
    const float* __restrict__ f1b0, const float* __restrict__ f1b1,
    const float* __restrict__ f1b2, const float* __restrict__ f1b3,
    const float* __restrict__ f1Wf,
    const float* __restrict__ f2b0, const float* __restrict__ f2b1,
    const float* __restrict__ f2b2, const float* __restrict__ f2b3,
    const float* __restrict__ f2Wf,
    float* __restrict__ out)
{
    __shared__ _Float16 act[2 * 64 * 64];   // 16 KB: two s-halves
    __shared__ float bl[192];               // biases: [layer*64 + feat]

    const int blk = blockIdx.x;
    const int lane = threadIdx.x;         // 0..63
    const int lo = lane & 15, q = lane >> 4;

    const float* xm = ws + WS_XM;
    const float* xarr = ws + WS_X;
    const float* x2arr = ws + WS_X2;
    const _Float16* wh = (const _Float16*)(ws + WS_H);
    const float lam = ws[WS_LAM];
    const float oml = 1.0f - lam;

    const int g = blk >> 4;               // 0..127
    const int w = blk & 15;               // 0..15
    const bool u2 = (g >= 64);
    const int base = (g & 63) << 6;
    const bool of_wave = (mode != 0) && (!u2) && (w == 15);

    const _Float16* W0h = wh + H_W0 + (u2 ? 2048 : 0);
    const _Float16* W1h = wh + (u2 ? H_NET : 0);
    const _Float16* W2h = W1h + H_W2;
    const _Float16* W3h = wh + H_W3 + (u2 ? 64 : 0);
    const float* B0 = u2 ? f2b0 : f1b0;
    const float* B1 = u2 ? f2b1 : f1b1;
    const float* B2 = u2 ? f2b2 : f1b2;
    const float* B3 = u2 ? f2b3 : f1b3;
    const float* WF = u2 ? f2Wf : f1Wf;
    const float p0 = u2 ? 1.5f : 1.1f;
    const float p1 = u2 ? 2.0f : 1.1f;
    const float p2 = u2 ? 2.5f : 1.5f;
    const float p3 = u2 ? 3.0f : 2.0f;
    const float p4 = u2 ? 3.5f : 2.5f;

    // biases -> LDS (single wave, in-order LDS => no barrier needed)
    bl[lane]       = B0[lane];
    bl[64 + lane]  = B1[lane];
    bl[128 + lane] = B2[lane];

    // ---- pin A-fragments + W3 (once per block) ----
    half8v A0w[4], A1w[4][2], A2w[4][2];
    half4v w3r[4];
    #pragma unroll
    for (int m = 0; m < 4; ++m) {
        A0w[m]    = *(const half8v*)(W0h + (16 * m + lo) * 32 + q * 8);
        A1w[m][0] = *(const half8v*)(W1h + (16 * m + lo) * 64 + q * 8);
        A1w[m][1] = *(const half8v*)(W1h + (16 * m + lo) * 64 + 32 + q * 8);
        A2w[m][0] = *(const half8v*)(W2h + (16 * m + lo) * 64 + q * 8);
        A2w[m][1] = *(const half8v*)(W2h + (16 * m + lo) * 64 + 32 + q * 8);
        w3r[m] = *(const half4v*)(W3h + 16 * m + 4 * q);
    }
    const float B3s = B3[0];
    const float wf0 = WF[0], wf1 = WF[1], wf2 = WF[2], wf3 = WF[3], wf4 = WF[4];

    // ---- per-lane item data: rows 16n+lo (B-build) / row lane (ownership) ----
    float xr_r[4], x2_r[4];
    half8v tpl[4];                        // pre-packed B template (h in halfs)
    #pragma unroll
    for (int n = 0; n < 4; ++n) {
        int idx = base + 16 * n + lo;
        xr_r[n] = mode ? (u2 ? x2arr[idx] : xarr[idx]) : oml * xm[idx];
        float4 h4 = ((const float4*)h_)[idx];
        half8v e;
        e[0] = (_Float16)0.0f;
        e[1] = (_Float16)h4.x; e[2] = (_Float16)h4.y;
        e[3] = (_Float16)h4.z; e[4] = (_Float16)h4.w;
        e[5] = (_Float16)0.0f; e[6] = (_Float16)0.0f; e[7] = (_Float16)0.0f;
        half8v z;
        #pragma unroll
        for (int t2 = 0; t2 < 8; ++t2) z[t2] = (_Float16)0.0f;
        tpl[n] = (q == 0) ? e : z;
        x2_r[n] = 0.0f;
    }
    if (of_wave) {
        #pragma unroll
        for (int n = 0; n < 4; ++n) x2_r[n] = x2arr[base + 16 * n + lo];
    }

    float xmax = 0.0f;
    if (u2) {
        if (mode) {
            float v = (lane < 16) ? ws[WS_PM16 + lane] : -1e30f;
            #pragma unroll
            for (int off = 32; off > 0; off >>= 1) v = fmaxf(v, __shfl_xor(v, off, 64));
            xmax = v + 10.0f;
        } else {
            const float* pm = ws + WS_PM;
            float v = fmaxf(fmaxf(pm[lane], pm[lane + 64]),
                            fmaxf(pm[lane + 128], pm[lane + 192]));
            #pragma unroll
            for (int off = 32; off > 0; off >>= 1) v = fmaxf(v, __shfl_xor(v, off, 64));
            xmax = oml * v + 10.0f;
        }
    }

    float acc = 0.0f;

    #pragma clang loop unroll(disable)
    for (int dp = 0; dp < 2; ++dp) {
        const int s0 = w + 32 * dp;                     // <= 47
        const bool live1 = (dp == 0) || (w < 3);        // s1 <= 50 check
        const int s1 = live1 ? (s0 + 16) : s0;
        const bool of1 = of_wave && (dp == 1);          // OF rides dead slot
        const float t0 = (ws[WS_CCS + s0] + 1.0f) * 0.5f;
        const float cw0 = ws[WS_CCW + s0];
        const float t1 = (ws[WS_CCS + s1] + 1.0f) * 0.5f;
        const float cw1 = live1 ? ws[WS_CCW + s1] : 0.0f;

        // ---- layer 0: both j at once (32 MFMAs); B built from template ----
        {
            half8v Bf0[2][4];
            #pragma unroll
            for (int j = 0; j < 2; ++j) {
                const float tj = j ? t1 : t0;
                #pragma unroll
                for (int n = 0; n < 4; ++n) {
                    float xin;
                    if (j == 1 && of1) xin = x2_r[n];
                    else if (u2)       xin = fmaf(tj, xmax - xr_r[n], xr_r[n]);
                    else               xin = xr_r[n] * tj;
                    half8v b = tpl[n];
                    b[0] = (_Float16)((q == 0) ? xin : 0.0f);
                    Bf0[j][n] = b;
                }
            }
            #pragma unroll
            for (int m = 0; m < 4; ++m) {
                float4v b0 = *(const float4v*)(bl + 16 * m + 4 * q);
                #pragma unroll
                for (int j = 0; j < 2; ++j)
                    #pragma unroll
                    for (int n = 0; n < 4; ++n) {
                        float4v c = __builtin_amdgcn_mfma_f32_16x16x32_f16(A0w[m], Bf0[j][n], b0, 0, 0, 0);
                        *(half4v*)(act + j * 4096 + swz(16 * n + lo, 2 * m + (q >> 1)) + 4 * (q & 1)) = pk_relu4(c);
                    }
            }
        }

        // ---- layer 1: j-sequential (Bf[2][4] live at a time) ----
        #pragma unroll
        for (int j = 0; j < 2; ++j) {
            half8v Bf[2][4];
            #pragma unroll
            for (int kb = 0; kb < 2; ++kb)
                #pragma unroll
                for (int n = 0; n < 4; ++n)
                    Bf[kb][n] = *(const half8v*)(act + j * 4096 + swz(16 * n + lo, 4 * kb + q));
            #pragma unroll
            for (int m = 0; m < 4; ++m) {
                float4v b1 = *(const float4v*)(bl + 64 + 16 * m + 4 * q);
                #pragma unroll
                for (int n = 0; n < 4; ++n) {
                    float4v c = __builtin_amdgcn_mfma_f32_16x16x32_f16(A1w[m][0], Bf[0][n], b1, 0, 0, 0);
                    c = __builtin_amdgcn_mfma_f32_16x16x32_f16(A1w[m][1], Bf[1][n], c, 0, 0, 0);
                    *(half4v*)(act + j * 4096 + swz(16 * n + lo, 2 * m + (q >> 1)) + 4 * (q & 1)) = pk_relu4(c);
                }
            }
        }

        // ---- layer 2 with fused W3-dot: j-sequential ----
        float part[2][4] = {{0.0f, 0.0f, 0.0f, 0.0f}, {0.0f, 0.0f, 0.0f, 0.0f}};
        #pragma unroll
        for (int j = 0; j < 2; ++j) {
            half8v Bf[2][4];
            #pragma unroll
            for (int kb = 0; kb < 2; ++kb)
                #pragma unroll
                for (int n = 0; n < 4; ++n)
                    Bf[kb][n] = *(const half8v*)(act + j * 4096 + swz(16 * n + lo, 4 * kb + q));
            #pragma unroll
            for (int m = 0; m < 4; ++m) {
                float4v b2 = *(const float4v*)(bl + 128 + 16 * m + 4 * q);
                #pragma unroll
                for (int n = 0; n < 4; ++n) {
                    float4v c = __builtin_amdgcn_mfma_f32_16x16x32_f16(A2w[m][0], Bf[0][n], b2, 0, 0, 0);
                    c = __builtin_amdgcn_mfma_f32_16x16x32_f16(A2w[m][1], Bf[1][n], c, 0, 0, 0);
                    #pragma unroll
                    for (int e = 0; e < 4; ++e)
                        part[j][n] = fmaf((float)w3r[m][e], fmaxf(c[e], 0.0f), part[j][n]);
                }
            }
        }

        // complete each row's dot across quads; lane keeps its own row (=lane)
        #pragma unroll
        for (int j = 0; j < 2; ++j)
            #pragma unroll
            for (int n = 0; n < 4; ++n) {
                part[j][n] += __shfl_xor(part[j][n], 16, 64);
                part[j][n] += __shfl_xor(part[j][n], 32, 64);
            }
        float y0 = B3s + (q == 0 ? part[0][0] : q == 1 ? part[0][1] : q == 2 ? part[0][2] : part[0][3]);
        float y1 = B3s + (q == 0 ? part[1][0] : q == 1 ? part[1][1] : q == 2 ? part[1][2] : part[1][3]);

        float val0 = tail5(y0, p0, p1, p2, p3, p4, wf0, wf1, wf2, wf3, wf4);
        float val1 = tail5(y1, p0, p1, p2, p3, p4, wf0, wf1, wf2, wf3, wf4);

        acc = fmaf(cw0, val0, acc);
        acc = fmaf(cw1, val1, acc);      // cw1 == 0 for dead/OF slots
        if (of1) out[BB + base + lane] = val1;
    }

    // ---- per-item epilogue: lane owns item base+lane (row 16q+lo == lane) ----
    const float x_l = (q == 0 ? xr_r[0] : q == 1 ? xr_r[1] : q == 2 ? xr_r[2] : xr_r[3]);
    if (!u2) {
        atomicAdd(out + base + lane, acc * x_l * 0.5f);
    } else {
        atomicAdd(out + 2 * BB + base + lane, acc * (xmax - x_l) * 0.5f * INV_ALPHA);
    }
}

extern "C" void kernel_launch(void* const* d_in, const int* in_sizes, int n_in,
                              void* d_out, int out_size, void* d_ws, size_t ws_size,
                              hipStream_t stream) {
    const float* x_  = (const float*)d_in[0];
    const float* h_  = (const float*)d_in[1];
    const float* lw  = (const float*)d_in[2];
    const float* sp  = (const float*)d_in[3];
    const float* f1W0 = (const float*)d_in[4];   const float* f1b0 = (const float*)d_in[5];
    const float* f1W1 = (const float*)d_in[6];   const float* f1b1 = (const float*)d_in[7];
    const float* f1W2 = (const float*)d_in[8];   const float* f1b2 = (const float*)d_in[9];
    const float* f1W3 = (const float*)d_in[10];  const float* f1b3 = (const float*)d_in[11];
    const float* f1Wf = (const float*)d_in[12];
    const float* f2W0 = (const float*)d_in[13];  const float* f2b0 = (const float*)d_in[14];
    const float* f2W1 = (const float*)d_in[15];  const float* f2b1 = (const float*)d_in[16];
    const float* f2W2 = (const float*)d_in[17];  const float* f2b2 = (const float*)d_in[18];
    const float* f2W3 = (const float*)d_in[19];  const float* f2b3 = (const float*)d_in[20];
    const float* f2Wf = (const float*)d_in[21];
    float* out = (float*)d_out;
    float* ws  = (float*)d_ws;

    k_setup<<<305, 256, 0, stream>>>(x_, lw, sp,
                                     f1W0, f1W1, f1W2, f1W3,
                                     f2W0, f2W1, f2W2, f2W3, ws, out);
    k_int<<<2048, 64, 0, stream>>>(0, ws, h_,
        f1b0, f1b1, f1b2, f1b3, f1Wf, f2b0, f2b1, f2b2, f2b3, f2Wf, out);
    k_pre<<<16, 256, 0, stream>>>(ws, out);
    k_int<<<2048, 64, 0, stream>>>(1, ws, h_,
        f1b0, f1b1, f1b2, f1b3, f1Wf, f2b0, f2b1, f2b2, f2b3, f2Wf, out);
}

// Round 6
// 137.699 us; speedup vs baseline: 1.4636x; 1.4636x over previous
//
#include <hip/hip_runtime.h>
#include <math.h>

typedef _Float16 half8v __attribute__((ext_vector_type(8)));
typedef _Float16 half4v __attribute__((ext_vector_type(4)));
typedef _Float16 half2v __attribute__((ext_vector_type(2)));
typedef float float4v __attribute__((ext_vector_type(4)));

// ---- problem constants ----
#define BB    4096
#define INV_ALPHA (1.0f/0.9f)

// ---- workspace float offsets ----
#define WS_CCW  0
#define WS_CCS  64
#define WS_LAM  128
#define WS_PM16 160     // 16 block-maxes of x2_step1 (written by k_pre)
#define WS_PM   256     // 256 block-maxes of xm
#define WS_XM   512
#define WS_X    (WS_XM + BB)
#define WS_X2   (WS_X + BB)
#define WS_H    16384   // halfs region starts at byte 65536
// half offsets within WS_H
#define H_NET   8192
#define H_W2    4096
#define H_W0    16384   // + net*2048 : [64 j][32 k] zero-padded
#define H_W3    20480   // + net*64

#if defined(__has_builtin)
#if __has_builtin(__builtin_amdgcn_rcpf)
#define FRCP(x) __builtin_amdgcn_rcpf(x)
#endif
#if __has_builtin(__builtin_amdgcn_exp2f)
#define FEXP2(x) __builtin_amdgcn_exp2f(x)
#endif
#if __has_builtin(__builtin_amdgcn_logf)
#define FLOG2(x) __builtin_amdgcn_logf(x)
#endif
#endif
#ifndef FRCP
#define FRCP(x) (1.0f / (x))
#endif
#ifndef FEXP2
#define FEXP2(x) exp2f(x)
#endif
#ifndef FLOG2
#define FLOG2(x) log2f(x)
#endif

// act: 64 rows x 64 halfs, 16B column-blocks XOR-swizzled by row
__device__ __forceinline__ int swz(int row, int cb) {
    return (row << 6) + (((cb ^ (row & 7)) & 7) << 3);
}

// relu + pack f32x4 -> f16x4
__device__ __forceinline__ half4v pk_relu4(float4v c) {
#if defined(__has_builtin) && __has_builtin(__builtin_amdgcn_cvt_pkrtz)
    half2v a = __builtin_bit_cast(half2v,
        __builtin_amdgcn_cvt_pkrtz(fmaxf(c[0], 0.0f), fmaxf(c[1], 0.0f)));
    half2v b = __builtin_bit_cast(half2v,
        __builtin_amdgcn_cvt_pkrtz(fmaxf(c[2], 0.0f), fmaxf(c[3], 0.0f)));
    half4v o; o[0] = a[0]; o[1] = a[1]; o[2] = b[0]; o[3] = b[1];
    return o;
#else
    half4v o;
    o[0] = (_Float16)fmaxf(c[0], 0.0f); o[1] = (_Float16)fmaxf(c[1], 0.0f);
    o[2] = (_Float16)fmaxf(c[2], 0.0f); o[3] = (_Float16)fmaxf(c[3], 0.0f);
    return o;
#endif
}

// integrand tail: ELU+1 -> 5 powers -> 1/(f+1) dot Wf -> relu
__device__ __forceinline__ float tail5(float y,
        float p0, float p1, float p2, float p3, float p4,
        float wf0, float wf1, float wf2, float wf3, float wf4) {
    if (y <= 0.0f) y = FEXP2(y * 1.44269504f) - 1.0f;   // elu
    float z = y + 1.0f;
    float lg = FLOG2(z);
    float g = wf0 * FRCP(FEXP2(p0 * lg) + 1.0f)
            + wf1 * FRCP(FEXP2(p1 * lg) + 1.0f)
            + wf2 * FRCP(FEXP2(p2 * lg) + 1.0f)
            + wf3 * FRCP(FEXP2(p3 * lg) + 1.0f)
            + wf4 * FRCP(FEXP2(p4 * lg) + 1.0f);
    return fmaxf(g, 0.0f);
}

// ---- fused setup: xm + maxes | weight repack | CC + lam | zero accumulators ----
__global__ void k_setup(const float* __restrict__ x_, const float* __restrict__ lw,
                        const float* __restrict__ sp,
                        const float* __restrict__ f1W0, const float* __restrict__ f1W1,
                        const float* __restrict__ f1W2, const float* __restrict__ f1W3,
                        const float* __restrict__ f2W0, const float* __restrict__ f2W1,
                        const float* __restrict__ f2W2, const float* __restrict__ f2W3,
                        float* __restrict__ ws, float* __restrict__ out) {
    _Float16* wh = (_Float16*)(ws + WS_H);
    const int blk = blockIdx.x, tid = threadIdx.x;
    if (blk < 256) {
        int wave = tid >> 6, lane = tid & 63;
        float vmax = -1e30f;
        for (int r = 0; r < 4; ++r) {
            int row = blk * 16 + wave * 4 + r;
            float v = 0.0f;
            for (int i = lane; i < 100; i += 64) v = fmaf(x_[row * 100 + i], lw[i], v);
            #pragma unroll
            for (int off = 32; off > 0; off >>= 1) v += __shfl_xor(v, off, 64);
            if (lane == 0) ws[WS_XM + row] = v;
            vmax = fmaxf(vmax, v);
        }
        __shared__ float sm[4];
        if (lane == 0) sm[wave] = vmax;
        __syncthreads();
        if (tid == 0)
            ws[WS_PM + blk] = fmaxf(fmaxf(sm[0], sm[1]), fmaxf(sm[2], sm[3]));
    } else if (blk < 272) {
        int t = (blk - 256) * 256 + tid;       // 0..4095
        wh[t]                = (_Float16)f1W1[t];
        wh[H_W2 + t]         = (_Float16)f1W2[t];
        wh[H_NET + t]        = (_Float16)f2W1[t];
        wh[H_NET + H_W2 + t] = (_Float16)f2W2[t];
        if (t < 2048) {
            int j = t >> 5, k = t & 31;
            wh[H_W0 + t]        = (k < 5) ? (_Float16)f1W0[j * 5 + k] : (_Float16)0.0f;
            wh[H_W0 + 2048 + t] = (k < 5) ? (_Float16)f2W0[j * 5 + k] : (_Float16)0.0f;
        }
        if (t < 64) {
            wh[H_W3 + t]      = (_Float16)f1W3[t];
            wh[H_W3 + 64 + t] = (_Float16)f2W3[t];
        }
    } else if (blk == 272) {
        if (tid == 64) ws[WS_LAM] = 1.0f / (1.0f + expf(-sp[0]));
        if (tid <= 50) {
            int s = tid;
            ws[WS_CCS + s] = cospif((float)s / 50.0f);
            float acc = 0.0f;
            for (int a = 0; a <= 50; ++a) {
                float w;
                if (a == 0) w = 1.0f;
                else if ((a & 1) == 0) w = 2.0f / (1.0f - (float)(a * a));
                else continue;
                float l;
                if (s == 0) l = 0.5f;
                else {
                    int m = (a * s) % 100;
                    l = cospif((float)m / 50.0f);
                    if (s == 50) l *= 0.5f;
                }
                acc += l * 0.04f * w;
            }
            ws[WS_CCW + s] = acc;
        }
    } else {
        // zero accumulation targets: out[0..BB) and out[2BB..3BB)
        int t = (blk - 273) * 256 + tid;       // 0..8191
        out[t < BB ? t : BB + t] = 0.0f;
    }
}

// between steps: x/x2 for step1, 16 partial maxes of x2, re-zero accumulators
__global__ void k_pre(float* __restrict__ ws, float* __restrict__ out) {
    int b = blockIdx.x * 256 + threadIdx.x;
    float lam = ws[WS_LAM];
    float m = ws[WS_XM + b];
    float xv  = (1.0f - lam) * m + lam * out[b];
    float x2v = (1.0f - lam) * m + lam * out[2 * BB + b];
    ws[WS_X + b] = xv;
    ws[WS_X2 + b] = x2v;
    out[b] = 0.0f;
    out[2 * BB + b] = 0.0f;
    __shared__ float red[256];
    red[threadIdx.x] = x2v;
    __syncthreads();
    #pragma unroll
    for (int off = 128; off > 0; off >>= 1) {
        if (threadIdx.x < off)
            red[threadIdx.x] = fmaxf(red[threadIdx.x], red[threadIdx.x + off]);
        __syncthreads();
    }
    if (threadIdx.x == 0) ws[WS_PM16 + blockIdx.x] = red[0];
}

// SPILL-FREE redesign. The pinned-A-fragment strategy exceeded the arch-VGPR
// allocation (~128) and spilled ~50-140 MB/launch to scratch (rounds 0-4).
// Now: weights live in LDS in FRAGMENT-MAJOR layout, re-read per pass with
// conflict-free lane-consecutive ds_read_b128. A 4-wave block (256 thr)
// shares one weight copy; each wave owns a private act slice (no barriers
// after staging). Block b: group g = b>>2 (0..127), waves w = (b&3)*4+wloc.
// Group g owns items [(g&63)*64,+64) of net (g>=64 ? f2:f1). Wave w takes
// s = w, w+16, w+32[, w+48 if w<3]; the w==15 f1 wave in mode 1 computes
// out_first in its dead 4th slot. One atomicAdd per item per wave.
__global__ __launch_bounds__(256, 2) void k_int(
    int mode, float* __restrict__ ws, const float* __restrict__ h_,
    const float* __restrict__ f1b0, const float* __restrict__ f1b1,
    const float* __restrict__ f1b2, const float* __restrict__ f1b3,
    const float* __restrict__ f1Wf,
    const float* __restrict__ f2b0, const float* __restrict__ f2b1,
    const float* __restrict__ f2b2, const float* __restrict__ f2b3,
    const float* __restrict__ f2Wf,
    float* __restrict__ out)
{
    __shared__ _Float16 act[4 * 64 * 64];   // 32 KB: per-wave slices
    __shared__ _Float16 w0f[4 * 16 * 8];    // 1 KB  : L0 frags (q==0 only)
    __shared__ _Float16 w1f[512 * 8];       // 8 KB  : L1 frags, frag-major
    __shared__ _Float16 w2f[512 * 8];       // 8 KB  : L2 frags, frag-major
    __shared__ float bl[192];               // biases: [layer*64 + feat]

    const int tid = threadIdx.x;
    const int blk = blockIdx.x;
    const int wloc = tid >> 6;
    const int lane = tid & 63;
    const int lo = lane & 15, q = lane >> 4;

    const int g = blk >> 2;               // 0..127
    const int w = (blk & 3) * 4 + wloc;   // 0..15
    const bool u2 = (g >= 64);
    const int base = (g & 63) << 6;
    const bool of_wave = (mode != 0) && (!u2) && (w == 15);

    const float* xm = ws + WS_XM;
    const float* xarr = ws + WS_X;
    const float* x2arr = ws + WS_X2;
    const _Float16* wh = (const _Float16*)(ws + WS_H);
    const float lam = ws[WS_LAM];
    const float oml = 1.0f - lam;

    const _Float16* W0h = wh + H_W0 + (u2 ? 2048 : 0);
    const _Float16* W1h = wh + (u2 ? H_NET : 0);
    const _Float16* W2h = W1h + H_W2;
    const _Float16* W3h = wh + H_W3 + (u2 ? 64 : 0);
    const float* B0 = u2 ? f2b0 : f1b0;
    const float* B1 = u2 ? f2b1 : f1b1;
    const float* B2 = u2 ? f2b2 : f1b2;
    const float* B3 = u2 ? f2b3 : f1b3;
    const float* WF = u2 ? f2Wf : f1Wf;
    const float p0 = u2 ? 1.5f : 1.1f;
    const float p1 = u2 ? 2.0f : 1.1f;
    const float p2 = u2 ? 2.5f : 1.5f;
    const float p3 = u2 ? 3.0f : 2.0f;
    const float p4 = u2 ? 3.5f : 2.5f;

    // ---- stage weights -> LDS, fragment-major (f = (m*2+kb)*64 + lane) ----
    #pragma unroll
    for (int f = tid; f < 512; f += 256) {
        int fm = f >> 7, fkb = (f >> 6) & 1, fl = f & 63;
        int flo = fl & 15, fq = fl >> 4;
        *(half8v*)(w1f + f * 8) =
            *(const half8v*)(W1h + (16 * fm + flo) * 64 + fkb * 32 + fq * 8);
        *(half8v*)(w2f + f * 8) =
            *(const half8v*)(W2h + (16 * fm + flo) * 64 + fkb * 32 + fq * 8);
    }
    if (tid < 64) {
        int fm = tid >> 4, flo = tid & 15;
        *(half8v*)(w0f + tid * 8) = *(const half8v*)(W0h + (16 * fm + flo) * 32);
    }
    if (tid < 192)
        bl[tid] = (tid < 64) ? B0[tid] : (tid < 128) ? B1[tid - 64] : B2[tid - 128];

    // ---- small per-lane pins (while staging is in flight) ----
    half4v w3r[4];
    #pragma unroll
    for (int m = 0; m < 4; ++m)
        w3r[m] = *(const half4v*)(W3h + 16 * m + 4 * q);
    const float B3s = B3[0];
    const float wf0 = WF[0], wf1 = WF[1], wf2 = WF[2], wf3 = WF[3], wf4 = WF[4];

    half8v zf;                            // zero fragment (shared)
    #pragma unroll
    for (int t2 = 0; t2 < 8; ++t2) zf[t2] = (_Float16)0.0f;

    float xr_r[4], x2_r[4];
    half8v tpl[4];                        // pre-packed B template (h in halfs)
    #pragma unroll
    for (int n = 0; n < 4; ++n) {
        int idx = base + 16 * n + lo;
        xr_r[n] = mode ? (u2 ? x2arr[idx] : xarr[idx]) : oml * xm[idx];
        float4 h4 = ((const float4*)h_)[idx];
        half8v e = zf;
        e[1] = (_Float16)h4.x; e[2] = (_Float16)h4.y;
        e[3] = (_Float16)h4.z; e[4] = (_Float16)h4.w;
        tpl[n] = (q == 0) ? e : zf;
        x2_r[n] = 0.0f;
    }
    if (of_wave) {
        #pragma unroll
        for (int n = 0; n < 4; ++n) x2_r[n] = x2arr[base + 16 * n + lo];
    }

    float xmax = 0.0f;
    if (u2) {
        if (mode) {
            float v = (lane < 16) ? ws[WS_PM16 + lane] : -1e30f;
            #pragma unroll
            for (int off = 32; off > 0; off >>= 1) v = fmaxf(v, __shfl_xor(v, off, 64));
            xmax = v + 10.0f;
        } else {
            const float* pm = ws + WS_PM;
            float v = fmaxf(fmaxf(pm[lane], pm[lane + 64]),
                            fmaxf(pm[lane + 128], pm[lane + 192]));
            #pragma unroll
            for (int off = 32; off > 0; off >>= 1) v = fmaxf(v, __shfl_xor(v, off, 64));
            xmax = oml * v + 10.0f;
        }
    }

    __syncthreads();                      // weights/biases staged

    _Float16* actw = act + (wloc << 12);  // private 4096-half slice
    const int np = (w < 3 || of_wave) ? 4 : 3;
    float acc = 0.0f;

    #pragma clang loop unroll(disable)
    for (int p = 0; p < np; ++p) {
        const bool of_iter = of_wave && (p == 3);
        float t = 0.0f, ccw_s = 0.0f;
        if (!of_iter) {
            int s = w + 16 * p;                     // <= 50 by construction
            t = (ws[WS_CCS + s] + 1.0f) * 0.5f;
            ccw_s = ws[WS_CCW + s];
        }

        // build B-operand for layer 0 from template (q==0 lanes carry k=0..4)
        half8v Bf0[4];
        #pragma unroll
        for (int n = 0; n < 4; ++n) {
            float xin;
            if (of_iter) xin = x2_r[n];
            else if (u2) xin = fmaf(t, xmax - xr_r[n], xr_r[n]);
            else         xin = xr_r[n] * t;
            half8v b = tpl[n];
            b[0] = (_Float16)((q == 0) ? xin : 0.0f);
            Bf0[n] = b;
        }

        // ---- layer 0: A-frag from LDS (broadcast reads, q==0 rows only) ----
        #pragma unroll
        for (int m = 0; m < 4; ++m) {
            half8v a0 = (q == 0) ? *(const half8v*)(w0f + (m * 16 + lo) * 8) : zf;
            float4v b0 = *(const float4v*)(bl + 16 * m + 4 * q);
            #pragma unroll
            for (int n = 0; n < 4; ++n) {
                float4v c = __builtin_amdgcn_mfma_f32_16x16x32_f16(a0, Bf0[n], b0, 0, 0, 0);
                *(half4v*)(actw + swz(16 * n + lo, 2 * m + (q >> 1)) + 4 * (q & 1)) = pk_relu4(c);
            }
        }

        // ---- layer 1: A-frags lane-consecutive from LDS ----
        {
            half8v Bf[2][4];
            #pragma unroll
            for (int kb = 0; kb < 2; ++kb)
                #pragma unroll
                for (int n = 0; n < 4; ++n)
                    Bf[kb][n] = *(const half8v*)(actw + swz(16 * n + lo, 4 * kb + q));
            #pragma unroll
            for (int m = 0; m < 4; ++m) {
                half8v a10 = *(const half8v*)(w1f + ((m * 2 + 0) * 64 + lane) * 8);
                half8v a11 = *(const half8v*)(w1f + ((m * 2 + 1) * 64 + lane) * 8);
                float4v b1 = *(const float4v*)(bl + 64 + 16 * m + 4 * q);
                #pragma unroll
                for (int n = 0; n < 4; ++n) {
                    float4v c = __builtin_amdgcn_mfma_f32_16x16x32_f16(a10, Bf[0][n], b1, 0, 0, 0);
                    c = __builtin_amdgcn_mfma_f32_16x16x32_f16(a11, Bf[1][n], c, 0, 0, 0);
                    *(half4v*)(actw + swz(16 * n + lo, 2 * m + (q >> 1)) + 4 * (q & 1)) = pk_relu4(c);
                }
            }
        }

        // ---- layer 2 with fused W3-dot ----
        float part[4] = {0.0f, 0.0f, 0.0f, 0.0f};
        {
            half8v Bf[2][4];
            #pragma unroll
            for (int kb = 0; kb < 2; ++kb)
                #pragma unroll
                for (int n = 0; n < 4; ++n)
                    Bf[kb][n] = *(const half8v*)(actw + swz(16 * n + lo, 4 * kb + q));
            #pragma unroll
            for (int m = 0; m < 4; ++m) {
                half8v a20 = *(const half8v*)(w2f + ((m * 2 + 0) * 64 + lane) * 8);
                half8v a21 = *(const half8v*)(w2f + ((m * 2 + 1) * 64 + lane) * 8);
                float4v b2 = *(const float4v*)(bl + 128 + 16 * m + 4 * q);
                #pragma unroll
                for (int n = 0; n < 4; ++n) {
                    float4v c = __builtin_amdgcn_mfma_f32_16x16x32_f16(a20, Bf[0][n], b2, 0, 0, 0);
                    c = __builtin_amdgcn_mfma_f32_16x16x32_f16(a21, Bf[1][n], c, 0, 0, 0);
                    #pragma unroll
                    for (int e = 0; e < 4; ++e)
                        part[n] = fmaf((float)w3r[m][e], fmaxf(c[e], 0.0f), part[n]);
                }
            }
        }

        // complete each row's dot across quads; lane keeps its own row (=lane)
        #pragma unroll
        for (int n = 0; n < 4; ++n) {
            part[n] += __shfl_xor(part[n], 16, 64);
            part[n] += __shfl_xor(part[n], 32, 64);
        }
        float y = B3s + (q == 0 ? part[0] : q == 1 ? part[1] : q == 2 ? part[2] : part[3]);

        float val = tail5(y, p0, p1, p2, p3, p4, wf0, wf1, wf2, wf3, wf4);

        if (of_iter) out[BB + base + lane] = val;
        else         acc = fmaf(ccw_s, val, acc);
    }

    // ---- per-item epilogue: lane owns item base+lane (row 16q+lo == lane) ----
    const float x_l = (q == 0 ? xr_r[0] : q == 1 ? xr_r[1] : q == 2 ? xr_r[2] : xr_r[3]);
    if (!u2) {
        atomicAdd(out + base + lane, acc * x_l * 0.5f);
    } else {
        atomicAdd(out + 2 * BB + base + lane, acc * (xmax - x_l) * 0.5f * INV_ALPHA);
    }
}

extern "C" void kernel_launch(void* const* d_in, const int* in_sizes, int n_in,
                              void* d_out, int out_size, void* d_ws, size_t ws_size,
                              hipStream_t stream) {
    const float* x_  = (const float*)d_in[0];
    const float* h_  = (const float*)d_in[1];
    const float* lw  = (const float*)d_in[2];
    const float* sp  = (const float*)d_in[3];
    const float* f1W0 = (const float*)d_in[4];   const float* f1b0 = (const float*)d_in[5];
    const float* f1W1 = (const float*)d_in[6];   const float* f1b1 = (const float*)d_in[7];
    const float* f1W2 = (const float*)d_in[8];   const float* f1b2 = (const float*)d_in[9];
    const float* f1W3 = (const float*)d_in[10];  const float* f1b3 = (const float*)d_in[11];
    const float* f1Wf = (const float*)d_in[12];
    const float* f2W0 = (const float*)d_in[13];  const float* f2b0 = (const float*)d_in[14];
    const float* f2W1 = (const float*)d_in[15];  const float* f2b1 = (const float*)d_in[16];
    const float* f2W2 = (const float*)d_in[17];  const float* f2b2 = (const float*)d_in[18];
    const float* f2W3 = (const float*)d_in[19];  const float* f2b3 = (const float*)d_in[20];
    const float* f2Wf = (const float*)d_in[21];
    float* out = (float*)d_out;
    float* ws  = (float*)d_ws;

    k_setup<<<305, 256, 0, stream>>>(x_, lw, sp,
                                     f1W0, f1W1, f1W2, f1W3,
                                     f2W0, f2W1, f2W2, f2W3, ws, out);
    k_int<<<512, 256, 0, stream>>>(0, ws, h_,
        f1b0, f1b1, f1b2, f1b3, f1Wf, f2b0, f2b1, f2b2, f2b3, f2Wf, out);
    k_pre<<<16, 256, 0, stream>>>(ws, out);
    k_int<<<512, 256, 0, stream>>>(1, ws, h_,
        f1b0, f1b1, f1b2, f1b3, f1Wf, f2b0, f2b1, f2b2, f2b3, f2Wf, out);
}